// Round 1
// baseline (571.085 us; speedup 1.0000x reference)
//
#include <hip/hip_runtime.h>

#define BB 4
#define NN 10000
#define MM 10000
#define PP 128
#define KS 32
#define KSC 4
#define ZZ 128

// workspace layout in floats (all offsets 16B-aligned)
#define OFF_PN 0                       // packed noisy  [B][N][4] (x,y,z,|p|^2)
#define OFF_PC (OFF_PN + BB*NN*4)      // packed clean  [B][M][4] (x,y,z,|c|^2)
#define OFF_FO (OFF_PC + BB*MM*4)      // f_origin      [B][P][4]
#define OFF_ZP (OFF_FO + BB*PP*4)      // zpart         [B][P][128]
#define OFF_FP (OFF_ZP + BB*PP*ZZ)     // f points      [B][P][K][4] (x,y,z,|f|^2)
#define OFF_GS (OFF_FP + BB*PP*KS*4)   // ground score  [B][P][K][4]
#define OFF_AC (OFF_GS + BB*PP*KS*4)   // loss accumulator [1]
// total ~2.07 MB of ws

#define FINF 1e30f

// ---------------- Stage 1: pack points with squared norms; zero accumulator ----
__global__ void k_pack(const float* __restrict__ noisy, const float* __restrict__ clean,
                       float* __restrict__ ws) {
    int t = blockIdx.x * blockDim.x + threadIdx.x;
    if (t == 0) ws[OFF_AC] = 0.0f;
    const int total = BB*NN + BB*MM;
    if (t >= total) return;
    if (t < BB*NN) {
        float x = noisy[t*3+0], y = noisy[t*3+1], z = noisy[t*3+2];
        float w = (x*x + y*y) + z*z;              // matches jnp.sum(p*p, axis=-1)
        ((float4*)(ws + OFF_PN))[t] = make_float4(x, y, z, w);
    } else {
        int u = t - BB*NN;
        float x = clean[u*3+0], y = clean[u*3+1], z = clean[u*3+2];
        float w = (x*x + y*y) + z*z;
        ((float4*)(ws + OFF_PC))[u] = make_float4(x, y, z, w);
    }
}

// ---------------- Stage 2: per sampled point: f_origin, feat MLP, zpart --------
// one wave per (b,p); 512 waves
__global__ void k_feat(const int* __restrict__ sidx,
                       const float* __restrict__ Wf1, const float* __restrict__ bf1,
                       const float* __restrict__ Wf2, const float* __restrict__ bf2,
                       const float* __restrict__ Ws1, const float* __restrict__ bs1,
                       float* __restrict__ ws) {
    int wave = (blockIdx.x * blockDim.x + threadIdx.x) >> 6;
    int lane = threadIdx.x & 63;
    if (wave >= BB*PP) return;
    int b = wave / PP, p = wave % PP;
    int si = sidx[p];
    float4 q = ((const float4*)(ws + OFF_PN))[b*NN + si];
    if (lane == 0) ((float4*)(ws + OFF_FO))[wave] = q;
    // hidden: relu(p @ Wf1 + bf1)   (64 units, one per lane)
    float h = bf1[lane];
    h = fmaf(q.x, Wf1[0*64 + lane], h);
    h = fmaf(q.y, Wf1[1*64 + lane], h);
    h = fmaf(q.z, Wf1[2*64 + lane], h);
    h = fmaxf(h, 0.0f);
    // feat = h @ Wf2 + bf2  (128 outs, 2 per lane)
    float fa = bf2[lane], fb = bf2[64 + lane];
    for (int i = 0; i < 64; ++i) {
        float hi = __shfl(h, i);
        fa = fmaf(hi, Wf2[i*ZZ + lane],      fa);
        fb = fmaf(hi, Wf2[i*ZZ + 64 + lane], fb);
    }
    // zpart = feat @ Ws1[3:,:] + bs1  (128 outs, 2 per lane)
    float za = bs1[lane], zb = bs1[64 + lane];
    for (int i = 0; i < 64; ++i) {
        float va = __shfl(fa, i);
        float vb = __shfl(fb, i);
        za = fmaf(va, Ws1[(3 + i)*128 + lane],       za);
        zb = fmaf(va, Ws1[(3 + i)*128 + 64 + lane],  zb);
        za = fmaf(vb, Ws1[(67 + i)*128 + lane],      za);
        zb = fmaf(vb, Ws1[(67 + i)*128 + 64 + lane], zb);
    }
    ws[OFF_ZP + wave*ZZ + lane]      = za;
    ws[OFF_ZP + wave*ZZ + 64 + lane] = zb;
}

// ---------------- Stage 3: knn1 — top-32 noisy neighbors of each sampled point -
// one block (256 thr) per (b,p); distances in LDS, 32 argmin-extraction rounds
__global__ __launch_bounds__(256) void k_knn1(const int* __restrict__ sidx, float* __restrict__ ws) {
    __shared__ float dist[NN];
    __shared__ float redv[4];
    __shared__ int   redi[4];
    __shared__ int   winIdx;
    int blk = blockIdx.x;            // = b*P + p
    int b = blk / PP, p = blk % PP;
    int tid = threadIdx.x;
    int si = sidx[p];
    const float4* pts = ((const float4*)(ws + OFF_PN)) + b*NN;
    float4 q = pts[si];
    for (int j = tid; j < NN; j += 256) {
        float4 r = pts[j];
        float dot = fmaf(q.z, r.z, fmaf(q.y, r.y, q.x*r.x));
        dist[j] = fmaf(dot, -2.0f, q.w + r.w);   // (q2+r2) - 2*dot, exact wrt ref
    }
    __syncthreads();
    float m = FINF; int mi = -1;
    for (int j = tid; j < NN; j += 256) {
        float d = dist[j];
        if (d < m) { m = d; mi = j; }
    }
    for (int r = 0; r < KS; ++r) {
        float mm = m; int mmi = mi;
        for (int off = 32; off > 0; off >>= 1) {
            float om = __shfl_down(mm, off);
            int   oi = __shfl_down(mmi, off);
            if (om < mm || (om == mm && oi < mmi)) { mm = om; mmi = oi; }
        }
        if ((tid & 63) == 0) { redv[tid >> 6] = mm; redi[tid >> 6] = mmi; }
        __syncthreads();
        if (tid == 0) {
            float bm = redv[0]; int bi = redi[0];
            for (int w2 = 1; w2 < 4; ++w2)
                if (redv[w2] < bm || (redv[w2] == bm && redi[w2] < bi)) { bm = redv[w2]; bi = redi[w2]; }
            winIdx = bi;
        }
        __syncthreads();
        int wi = winIdx;
        if (tid == 0) ((float4*)(ws + OFF_FP))[blk*KS + r] = pts[wi];
        if (mi == wi) {            // owner re-scans its stride subset
            dist[wi] = FINF;
            m = FINF; mi = -1;
            for (int j = tid; j < NN; j += 256) {
                float d = dist[j];
                if (d < m) { m = d; mi = j; }
            }
        }
        __syncthreads();
    }
}

// ---------------- Stage 4: knn2 — top-4 clean neighbors + ground score ---------
// 8 lanes per query, 8 queries per wave, 1 wave per block; 2048 blocks
__global__ __launch_bounds__(64) void k_knn2(const float* __restrict__ clean, float* __restrict__ ws) {
    int lane = threadIdx.x;
    int grp = lane >> 3, sub = lane & 7;
    int g = blockIdx.x * 8 + grp;                 // query index in [0, B*P*K)
    int b = g >> 12;                              // P*K = 4096
    float4 f4 = ((const float4*)(ws + OFF_FP))[g];
    float fx = f4.x, fy = f4.y, fz = f4.z, f2 = f4.w;
    const float4* pts = ((const float4*)(ws + OFF_PC)) + b*MM;
    float s0 = FINF, s1 = FINF, s2 = FINF, s3 = FINF;
    int   i0 = -1,   i1 = -1,   i2 = -1,   i3 = -1;
    #pragma unroll 2
    for (int c = 0; c < MM/8; ++c) {
        int j = c*8 + sub;
        float4 r = pts[j];
        float dot = fmaf(fz, r.z, fmaf(fy, r.y, fx*r.x));
        float d = fmaf(dot, -2.0f, f2 + r.w);
        if (d < s3) {
            if (d < s2) {
                s3 = s2; i3 = i2;
                if (d < s1) {
                    s2 = s1; i2 = i1;
                    if (d < s0) { s1 = s0; i1 = i0; s0 = d; i0 = j; }
                    else        { s1 = d;  i1 = j; }
                } else { s2 = d; i2 = j; }
            } else { s3 = d; i3 = j; }
        }
    }
    // merge 8 lanes' sorted lists: 4 extraction rounds
    float gx = 0.f, gy = 0.f, gz = 0.f;
    for (int r = 0; r < KSC; ++r) {
        float bk = s0; int bi = i0; int bl = lane;
        for (int off = 1; off < 8; off <<= 1) {
            float ok = __shfl_xor(bk, off);
            int   oi = __shfl_xor(bi, off);
            int   ol = __shfl_xor(bl, off);
            if (ok < bk || (ok == bk && oi < bi)) { bk = ok; bi = oi; bl = ol; }
        }
        const float* cp = clean + (size_t)(b*MM + bi)*3;
        gx += cp[0] - fx; gy += cp[1] - fy; gz += cp[2] - fz;
        if (lane == bl) { s0 = s1; i0 = i1; s1 = s2; i1 = i2; s2 = s3; i2 = i3; s3 = FINF; i3 = -1; }
    }
    if (sub == 0) {
        float* gsp = ws + OFF_GS + (size_t)g*4;
        gsp[0] = gx*0.25f; gsp[1] = gy*0.25f; gsp[2] = gz*0.25f;
    }
}

// ---------------- Stage 5: score MLP + loss ------------------------------------
// 64 threads/block, thread-per-f-point; Ws2 staged in LDS (uniform broadcast reads)
__global__ __launch_bounds__(64) void k_mlp(const float* __restrict__ Ws1,
                                            const float* __restrict__ Ws2, const float* __restrict__ bs2,
                                            const float* __restrict__ Ws3, const float* __restrict__ bs3,
                                            float* __restrict__ ws) {
    __shared__ float  sW1[3][128];
    __shared__ float4 sW2[128][16];
    __shared__ float  sB2[64];
    __shared__ float  sW3[64][3];
    __shared__ float  sB3[3];
    __shared__ float  sZP[2][128];
    int tid = threadIdx.x;
    for (int u = tid; u < 384; u += 64) sW1[u >> 7][u & 127] = Ws1[u];
    for (int u = tid; u < 2048; u += 64) ((float4*)sW2)[u] = ((const float4*)Ws2)[u];
    sB2[tid] = bs2[tid];
    for (int u = tid; u < 192; u += 64) ((float*)sW3)[u] = Ws3[u];
    if (tid < 3) sB3[tid] = bs3[tid];
    for (int u = tid; u < 256; u += 64)
        sZP[u >> 7][u & 127] = ws[OFF_ZP + (blockIdx.x*2 + (u >> 7))*ZZ + (u & 127)];
    __syncthreads();

    int g = blockIdx.x*64 + tid;
    float4 f4 = ((const float4*)(ws + OFF_FP))[g];
    float4 fo = ((const float4*)(ws + OFF_FO))[g >> 5];
    float x0 = f4.x - fo.x, x1 = f4.y - fo.y, x2 = f4.z - fo.z;
    const float* zp = sZP[tid >> 5];

    float4 a[16];
    #pragma unroll
    for (int qq = 0; qq < 16; ++qq) a[qq] = make_float4(0.f, 0.f, 0.f, 0.f);

    for (int i = 0; i < 128; ++i) {
        float h1 = fmaf(x2, sW1[2][i], fmaf(x1, sW1[1][i], fmaf(x0, sW1[0][i], zp[i])));
        h1 = fmaxf(h1, 0.0f);
        #pragma unroll
        for (int qq = 0; qq < 16; ++qq) {
            float4 w = sW2[i][qq];
            a[qq].x = fmaf(h1, w.x, a[qq].x);
            a[qq].y = fmaf(h1, w.y, a[qq].y);
            a[qq].z = fmaf(h1, w.z, a[qq].z);
            a[qq].w = fmaf(h1, w.w, a[qq].w);
        }
    }
    float e0 = 0.f, e1 = 0.f, e2 = 0.f;
    #pragma unroll
    for (int qq = 0; qq < 16; ++qq) {
        float av[4] = {a[qq].x, a[qq].y, a[qq].z, a[qq].w};
        #pragma unroll
        for (int c = 0; c < 4; ++c) {
            int j = qq*4 + c;
            float h2 = fmaxf(av[c] + sB2[j], 0.0f);
            e0 = fmaf(h2, sW3[j][0], e0);
            e1 = fmaf(h2, sW3[j][1], e1);
            e2 = fmaf(h2, sW3[j][2], e2);
        }
    }
    e0 += sB3[0]; e1 += sB3[1]; e2 += sB3[2];
    const float* gsp = ws + OFF_GS + (size_t)g*4;
    float d0 = e0 - gsp[0], d1 = e1 - gsp[1], d2 = e2 - gsp[2];
    float t = ((d0*d0 + d1*d1) + d2*d2) * 100.0f;   // 1/SIGMA folds to exactly 100.0f
    for (int off = 32; off > 0; off >>= 1) t += __shfl_down(t, off);
    if (tid == 0) atomicAdd(ws + OFF_AC, t);
}

// ---------------- Stage 6: finalize --------------------------------------------
__global__ void k_fin(const float* __restrict__ ws, float* __restrict__ out) {
    if (threadIdx.x == 0 && blockIdx.x == 0)
        out[0] = ws[OFF_AC] * (1.0f / 32768.0f);    // * 0.5 / (B*P*K), exact pow2
}

extern "C" void kernel_launch(void* const* d_in, const int* in_sizes, int n_in,
                              void* d_out, int out_size, void* d_ws, size_t ws_size,
                              hipStream_t stream) {
    const float* noisy = (const float*)d_in[0];
    const float* clean = (const float*)d_in[1];
    const int*   sidx  = (const int*)  d_in[2];
    const float* Wf1 = (const float*)d_in[3];
    const float* bf1 = (const float*)d_in[4];
    const float* Wf2 = (const float*)d_in[5];
    const float* bf2 = (const float*)d_in[6];
    const float* Ws1 = (const float*)d_in[7];
    const float* bs1 = (const float*)d_in[8];
    const float* Ws2 = (const float*)d_in[9];
    const float* bs2 = (const float*)d_in[10];
    const float* Ws3 = (const float*)d_in[11];
    const float* bs3 = (const float*)d_in[12];
    float* ws  = (float*)d_ws;
    float* out = (float*)d_out;

    k_pack<<<(BB*NN + BB*MM + 255)/256, 256, 0, stream>>>(noisy, clean, ws);
    k_feat<<<(BB*PP*64)/256, 256, 0, stream>>>(sidx, Wf1, bf1, Wf2, bf2, Ws1, bs1, ws);
    k_knn1<<<BB*PP, 256, 0, stream>>>(sidx, ws);
    k_knn2<<<(BB*PP*KS)/8, 64, 0, stream>>>(clean, ws);
    k_mlp<<<(BB*PP*KS)/64, 64, 0, stream>>>(Ws1, Ws2, bs2, Ws3, bs3, ws);
    k_fin<<<1, 64, 0, stream>>>(ws, out);
}

// Round 2
// 294.702 us; speedup vs baseline: 1.9378x; 1.9378x over previous
//
#include <hip/hip_runtime.h>

#define BB 4
#define NN 10000
#define MM 10000
#define PP 128
#define KS 32
#define KSC 4
#define ZZ 128

// workspace layout in floats (all offsets 16B-aligned)
#define OFF_PN 0                       // packed noisy  [B][N][4] (x,y,z,|p|^2)
#define OFF_PC (OFF_PN + BB*NN*4)      // packed clean  [B][M][4] (x,y,z,|c|^2)
#define OFF_FO (OFF_PC + BB*MM*4)      // f_origin      [B][P][4]
#define OFF_ZP (OFF_FO + BB*PP*4)      // zpart         [B][P][128]
#define OFF_FP (OFF_ZP + BB*PP*ZZ)     // f points      [B][P][K][4] (x,y,z,|f|^2)
#define OFF_GS (OFF_FP + BB*PP*KS*4)   // ground score  [B][P][K][4]
#define OFF_AC (OFF_GS + BB*PP*KS*4)   // loss accumulator [1]
#define OFF_K2 (OFF_AC + 4)            // knn2 partial idx [B*P*K][NCH][4] ushort (2 MB)

#define NCH 16
#define MCH (MM/NCH)                   // 625
#define FINF 1e30f

// ---------------- Stage 1: pack points with squared norms; zero accumulator ----
__global__ void k_pack(const float* __restrict__ noisy, const float* __restrict__ clean,
                       float* __restrict__ ws) {
    int t = blockIdx.x * blockDim.x + threadIdx.x;
    if (t == 0) ws[OFF_AC] = 0.0f;
    const int total = BB*NN + BB*MM;
    if (t >= total) return;
    if (t < BB*NN) {
        float x = noisy[t*3+0], y = noisy[t*3+1], z = noisy[t*3+2];
        float w = (x*x + y*y) + z*z;              // matches jnp.sum(p*p, axis=-1)
        ((float4*)(ws + OFF_PN))[t] = make_float4(x, y, z, w);
    } else {
        int u = t - BB*NN;
        float x = clean[u*3+0], y = clean[u*3+1], z = clean[u*3+2];
        float w = (x*x + y*y) + z*z;
        ((float4*)(ws + OFF_PC))[u] = make_float4(x, y, z, w);
    }
}

// ---------------- Stage 2: per sampled point: f_origin, feat MLP, zpart --------
// one wave per (b,p); 512 waves
__global__ void k_feat(const int* __restrict__ sidx,
                       const float* __restrict__ Wf1, const float* __restrict__ bf1,
                       const float* __restrict__ Wf2, const float* __restrict__ bf2,
                       const float* __restrict__ Ws1, const float* __restrict__ bs1,
                       float* __restrict__ ws) {
    int wave = (blockIdx.x * blockDim.x + threadIdx.x) >> 6;
    int lane = threadIdx.x & 63;
    if (wave >= BB*PP) return;
    int b = wave / PP, p = wave % PP;
    int si = sidx[p];
    float4 q = ((const float4*)(ws + OFF_PN))[b*NN + si];
    if (lane == 0) ((float4*)(ws + OFF_FO))[wave] = q;
    // hidden: relu(p @ Wf1 + bf1)   (64 units, one per lane)
    float h = bf1[lane];
    h = fmaf(q.x, Wf1[0*64 + lane], h);
    h = fmaf(q.y, Wf1[1*64 + lane], h);
    h = fmaf(q.z, Wf1[2*64 + lane], h);
    h = fmaxf(h, 0.0f);
    // feat = h @ Wf2 + bf2  (128 outs, 2 per lane)
    float fa = bf2[lane], fb = bf2[64 + lane];
    for (int i = 0; i < 64; ++i) {
        float hi = __shfl(h, i);
        fa = fmaf(hi, Wf2[i*ZZ + lane],      fa);
        fb = fmaf(hi, Wf2[i*ZZ + 64 + lane], fb);
    }
    // zpart = feat @ Ws1[3:,:] + bs1  (128 outs, 2 per lane)
    float za = bs1[lane], zb = bs1[64 + lane];
    for (int i = 0; i < 64; ++i) {
        float va = __shfl(fa, i);
        float vb = __shfl(fb, i);
        za = fmaf(va, Ws1[(3 + i)*128 + lane],       za);
        zb = fmaf(va, Ws1[(3 + i)*128 + 64 + lane],  zb);
        za = fmaf(vb, Ws1[(67 + i)*128 + lane],      za);
        zb = fmaf(vb, Ws1[(67 + i)*128 + 64 + lane], zb);
    }
    ws[OFF_ZP + wave*ZZ + lane]      = za;
    ws[OFF_ZP + wave*ZZ + 64 + lane] = zb;
}

// ---------------- Stage 3: knn1 — top-32 noisy neighbors of each sampled point -
// one block (256 thr) per (b,p); distances in LDS, 32 argmin-extraction rounds
__global__ __launch_bounds__(256) void k_knn1(const int* __restrict__ sidx, float* __restrict__ ws) {
    __shared__ float dist[NN];
    __shared__ float redv[4];
    __shared__ int   redi[4];
    __shared__ int   winIdx;
    int blk = blockIdx.x;            // = b*P + p
    int b = blk / PP, p = blk % PP;
    int tid = threadIdx.x;
    int si = sidx[p];
    const float4* pts = ((const float4*)(ws + OFF_PN)) + b*NN;
    float4 q = pts[si];
    for (int j = tid; j < NN; j += 256) {
        float4 r = pts[j];
        float dot = fmaf(q.z, r.z, fmaf(q.y, r.y, q.x*r.x));
        dist[j] = fmaf(dot, -2.0f, q.w + r.w);   // (q2+r2) - 2*dot, exact wrt ref
    }
    __syncthreads();
    float m = FINF; int mi = -1;
    for (int j = tid; j < NN; j += 256) {
        float d = dist[j];
        if (d < m) { m = d; mi = j; }
    }
    for (int r = 0; r < KS; ++r) {
        float mm = m; int mmi = mi;
        for (int off = 32; off > 0; off >>= 1) {
            float om = __shfl_down(mm, off);
            int   oi = __shfl_down(mmi, off);
            if (om < mm || (om == mm && oi < mmi)) { mm = om; mmi = oi; }
        }
        if ((tid & 63) == 0) { redv[tid >> 6] = mm; redi[tid >> 6] = mmi; }
        __syncthreads();
        if (tid == 0) {
            float bm = redv[0]; int bi = redi[0];
            for (int w2 = 1; w2 < 4; ++w2)
                if (redv[w2] < bm || (redv[w2] == bm && redi[w2] < bi)) { bm = redv[w2]; bi = redi[w2]; }
            winIdx = bi;
        }
        __syncthreads();
        int wi = winIdx;
        if (tid == 0) ((float4*)(ws + OFF_FP))[blk*KS + r] = pts[wi];
        if (mi == wi) {            // owner re-scans its stride subset
            dist[wi] = FINF;
            m = FINF; mi = -1;
            for (int j = tid; j < NN; j += 256) {
                float d = dist[j];
                if (d < m) { m = d; mi = j; }
            }
        }
        __syncthreads();
    }
}

// ---------------- Stage 4a: knn2 chunk pass — per-chunk top-4 candidates -------
// 512 blocks = 32 query-groups (512 queries) x 16 M-chunks; Q=2 queries/thread.
// Clean chunk staged in LDS; all lanes broadcast-read the same point.
__global__ __launch_bounds__(256) void k_knn2a(float* __restrict__ ws) {
    __shared__ float4 sp[MCH];
    int gq = blockIdx.x / NCH;       // query group (512 queries each)
    int ch = blockIdx.x % NCH;
    int tid = threadIdx.x;
    int q0 = gq * 512 + tid;         // this thread's queries: q0, q0+256 (same batch)
    int b  = q0 >> 12;               // P*K = 4096 per batch; 512 | 4096 so uniform
    const float4* pts = ((const float4*)(ws + OFF_PC)) + b*MM + ch*MCH;
    for (int u = tid; u < MCH; u += 256) sp[u] = pts[u];
    __syncthreads();
    float4 fA = ((const float4*)(ws + OFF_FP))[q0];
    float4 fB = ((const float4*)(ws + OFF_FP))[q0 + 256];
    float sA0=FINF,sA1=FINF,sA2=FINF,sA3=FINF;
    float sB0=FINF,sB1=FINF,sB2=FINF,sB3=FINF;
    int   iA0=0,iA1=0,iA2=0,iA3=0, iB0=0,iB1=0,iB2=0,iB3=0;
    #pragma unroll 4
    for (int j = 0; j < MCH; ++j) {
        float4 r = sp[j];
        {
            float dot = fmaf(fA.z, r.z, fmaf(fA.y, r.y, fA.x*r.x));
            float d = fmaf(dot, -2.0f, fA.w + r.w);
            if (d < sA3) {
                if (d < sA2) { sA3=sA2; iA3=iA2;
                    if (d < sA1) { sA2=sA1; iA2=iA1;
                        if (d < sA0) { sA1=sA0; iA1=iA0; sA0=d; iA0=j; }
                        else         { sA1=d;  iA1=j; }
                    } else { sA2=d; iA2=j; }
                } else { sA3=d; iA3=j; }
            }
        }
        {
            float dot = fmaf(fB.z, r.z, fmaf(fB.y, r.y, fB.x*r.x));
            float d = fmaf(dot, -2.0f, fB.w + r.w);
            if (d < sB3) {
                if (d < sB2) { sB3=sB2; iB3=iB2;
                    if (d < sB1) { sB2=sB1; iB2=iB1;
                        if (d < sB0) { sB1=sB0; iB1=iB0; sB0=d; iB0=j; }
                        else         { sB1=d;  iB1=j; }
                    } else { sB2=d; iB2=j; }
                } else { sB3=d; iB3=j; }
            }
        }
    }
    int off = ch * MCH;
    ushort4* kbuf = (ushort4*)(ws + OFF_K2);
    kbuf[q0*NCH + ch]        = make_ushort4((unsigned short)(iA0+off), (unsigned short)(iA1+off),
                                            (unsigned short)(iA2+off), (unsigned short)(iA3+off));
    kbuf[(q0+256)*NCH + ch]  = make_ushort4((unsigned short)(iB0+off), (unsigned short)(iB1+off),
                                            (unsigned short)(iB2+off), (unsigned short)(iB3+off));
}

// ---------------- Stage 4b: knn2 merge — exact top-4 of 64 candidates ----------
// one thread per query; (d, idx)-lexicographic order == stable jax top_k
__global__ __launch_bounds__(128) void k_knn2b(float* __restrict__ ws) {
    int q = blockIdx.x * 128 + threadIdx.x;
    int b = q >> 12;
    float4 f4 = ((const float4*)(ws + OFF_FP))[q];
    float fx = f4.x, fy = f4.y, fz = f4.z, f2 = f4.w;
    const float4* pts = ((const float4*)(ws + OFF_PC)) + b*MM;
    const ushort4* kbuf = ((const ushort4*)(ws + OFF_K2)) + q*NCH;
    float s0=FINF,s1=FINF,s2=FINF,s3=FINF;
    int   i0=-1,  i1=-1,  i2=-1,  i3=-1;
    #pragma unroll 4
    for (int c = 0; c < NCH; ++c) {
        ushort4 cand = kbuf[c];
        int ids[4] = {(int)cand.x, (int)cand.y, (int)cand.z, (int)cand.w};
        #pragma unroll
        for (int r = 0; r < 4; ++r) {
            int jj = ids[r];
            float4 rp = pts[jj];
            float dot = fmaf(fz, rp.z, fmaf(fy, rp.y, fx*rp.x));
            float d = fmaf(dot, -2.0f, f2 + rp.w);
            bool l3 = (d < s3) || (d == s3 && jj < i3);
            if (l3) {
                bool l2 = (d < s2) || (d == s2 && jj < i2);
                if (l2) { s3=s2; i3=i2;
                    bool l1 = (d < s1) || (d == s1 && jj < i1);
                    if (l1) { s2=s1; i2=i1;
                        bool l0 = (d < s0) || (d == s0 && jj < i0);
                        if (l0) { s1=s0; i1=i0; s0=d; i0=jj; }
                        else    { s1=d;  i1=jj; }
                    } else { s2=d; i2=jj; }
                } else { s3=d; i3=jj; }
            }
        }
    }
    // ground score: accumulate in rank order (matches reference gather order)
    float gx=0.f, gy=0.f, gz=0.f;
    float4 n0 = pts[i0], n1 = pts[i1], n2 = pts[i2], n3 = pts[i3];
    gx += n0.x - fx; gy += n0.y - fy; gz += n0.z - fz;
    gx += n1.x - fx; gy += n1.y - fy; gz += n1.z - fz;
    gx += n2.x - fx; gy += n2.y - fy; gz += n2.z - fz;
    gx += n3.x - fx; gy += n3.y - fy; gz += n3.z - fz;
    float* gsp = ws + OFF_GS + (size_t)q*4;
    gsp[0] = gx*0.25f; gsp[1] = gy*0.25f; gsp[2] = gz*0.25f;
}

// ---------------- Stage 5: score MLP + loss ------------------------------------
// 64 threads/block, thread-per-f-point; Ws2 staged in LDS (uniform broadcast reads)
__global__ __launch_bounds__(64) void k_mlp(const float* __restrict__ Ws1,
                                            const float* __restrict__ Ws2, const float* __restrict__ bs2,
                                            const float* __restrict__ Ws3, const float* __restrict__ bs3,
                                            float* __restrict__ ws) {
    __shared__ float  sW1[3][128];
    __shared__ float4 sW2[128][16];
    __shared__ float  sB2[64];
    __shared__ float  sW3[64][3];
    __shared__ float  sB3[3];
    __shared__ float  sZP[2][128];
    int tid = threadIdx.x;
    for (int u = tid; u < 384; u += 64) sW1[u >> 7][u & 127] = Ws1[u];
    for (int u = tid; u < 2048; u += 64) ((float4*)sW2)[u] = ((const float4*)Ws2)[u];
    sB2[tid] = bs2[tid];
    for (int u = tid; u < 192; u += 64) ((float*)sW3)[u] = Ws3[u];
    if (tid < 3) sB3[tid] = bs3[tid];
    for (int u = tid; u < 256; u += 64)
        sZP[u >> 7][u & 127] = ws[OFF_ZP + (blockIdx.x*2 + (u >> 7))*ZZ + (u & 127)];
    __syncthreads();

    int g = blockIdx.x*64 + tid;
    float4 f4 = ((const float4*)(ws + OFF_FP))[g];
    float4 fo = ((const float4*)(ws + OFF_FO))[g >> 5];
    float x0 = f4.x - fo.x, x1 = f4.y - fo.y, x2 = f4.z - fo.z;
    const float* zp = sZP[tid >> 5];

    float4 a[16];
    #pragma unroll
    for (int qq = 0; qq < 16; ++qq) a[qq] = make_float4(0.f, 0.f, 0.f, 0.f);

    for (int i = 0; i < 128; ++i) {
        float h1 = fmaf(x2, sW1[2][i], fmaf(x1, sW1[1][i], fmaf(x0, sW1[0][i], zp[i])));
        h1 = fmaxf(h1, 0.0f);
        #pragma unroll
        for (int qq = 0; qq < 16; ++qq) {
            float4 w = sW2[i][qq];
            a[qq].x = fmaf(h1, w.x, a[qq].x);
            a[qq].y = fmaf(h1, w.y, a[qq].y);
            a[qq].z = fmaf(h1, w.z, a[qq].z);
            a[qq].w = fmaf(h1, w.w, a[qq].w);
        }
    }
    float e0 = 0.f, e1 = 0.f, e2 = 0.f;
    #pragma unroll
    for (int qq = 0; qq < 16; ++qq) {
        float av[4] = {a[qq].x, a[qq].y, a[qq].z, a[qq].w};
        #pragma unroll
        for (int c = 0; c < 4; ++c) {
            int j = qq*4 + c;
            float h2 = fmaxf(av[c] + sB2[j], 0.0f);
            e0 = fmaf(h2, sW3[j][0], e0);
            e1 = fmaf(h2, sW3[j][1], e1);
            e2 = fmaf(h2, sW3[j][2], e2);
        }
    }
    e0 += sB3[0]; e1 += sB3[1]; e2 += sB3[2];
    const float* gsp = ws + OFF_GS + (size_t)g*4;
    float d0 = e0 - gsp[0], d1 = e1 - gsp[1], d2 = e2 - gsp[2];
    float t = ((d0*d0 + d1*d1) + d2*d2) * 100.0f;   // 1/SIGMA folds to exactly 100.0f
    for (int off = 32; off > 0; off >>= 1) t += __shfl_down(t, off);
    if (tid == 0) atomicAdd(ws + OFF_AC, t);
}

// ---------------- Stage 6: finalize --------------------------------------------
__global__ void k_fin(const float* __restrict__ ws, float* __restrict__ out) {
    if (threadIdx.x == 0 && blockIdx.x == 0)
        out[0] = ws[OFF_AC] * (1.0f / 32768.0f);    // * 0.5 / (B*P*K), exact pow2
}

extern "C" void kernel_launch(void* const* d_in, const int* in_sizes, int n_in,
                              void* d_out, int out_size, void* d_ws, size_t ws_size,
                              hipStream_t stream) {
    const float* noisy = (const float*)d_in[0];
    const float* clean = (const float*)d_in[1];
    const int*   sidx  = (const int*)  d_in[2];
    const float* Wf1 = (const float*)d_in[3];
    const float* bf1 = (const float*)d_in[4];
    const float* Wf2 = (const float*)d_in[5];
    const float* bf2 = (const float*)d_in[6];
    const float* Ws1 = (const float*)d_in[7];
    const float* bs1 = (const float*)d_in[8];
    const float* Ws2 = (const float*)d_in[9];
    const float* bs2 = (const float*)d_in[10];
    const float* Ws3 = (const float*)d_in[11];
    const float* bs3 = (const float*)d_in[12];
    float* ws  = (float*)d_ws;
    float* out = (float*)d_out;

    k_pack<<<(BB*NN + BB*MM + 255)/256, 256, 0, stream>>>(noisy, clean, ws);
    k_feat<<<(BB*PP*64)/256, 256, 0, stream>>>(sidx, Wf1, bf1, Wf2, bf2, Ws1, bs1, ws);
    k_knn1<<<BB*PP, 256, 0, stream>>>(sidx, ws);
    k_knn2a<<<(BB*PP*KS/512)*NCH, 256, 0, stream>>>(ws);
    k_knn2b<<<(BB*PP*KS)/128, 128, 0, stream>>>(ws);
    k_mlp<<<(BB*PP*KS)/64, 64, 0, stream>>>(Ws1, Ws2, bs2, Ws3, bs3, ws);
    k_fin<<<1, 64, 0, stream>>>(ws, out);
}